// Round 1
// 786.740 us; speedup vs baseline: 1.0214x; 1.0214x over previous
//
#include <hip/hip_runtime.h>
#include <math.h>

// Problem constants (reference: B=32, L=2048)
#define LLEN 2048
#define BATCH 32
#define N_PTS (LLEN - 2)     // 2046 embedded points
#define N_DEATH (LLEN - 3)   // 2045 MST edges / deaths
#define SORT_N 2048
#define TPB 256              // 4 waves, one per SIMD
#define PT 8                 // elements per thread
#define NW 4                 // waves per block
#define BIG 1e30f
#define TOPO_BYTES ((size_t)64 * N_DEATH * 4)   // 523,520 B

// Wave64 unsigned-min via DPP (VALU pipe). Result valid in lane 63.
__device__ __forceinline__ unsigned dpp_umin6(unsigned v) {
    unsigned t;
    t = (unsigned)__builtin_amdgcn_update_dpp(-1, (int)v, 0x111, 0xF, 0xF, false); // row_shr:1
    v = t < v ? t : v;
    t = (unsigned)__builtin_amdgcn_update_dpp(-1, (int)v, 0x112, 0xF, 0xF, false); // row_shr:2
    v = t < v ? t : v;
    t = (unsigned)__builtin_amdgcn_update_dpp(-1, (int)v, 0x114, 0xF, 0xF, false); // row_shr:4
    v = t < v ? t : v;
    t = (unsigned)__builtin_amdgcn_update_dpp(-1, (int)v, 0x118, 0xF, 0xF, false); // row_shr:8
    v = t < v ? t : v;
    t = (unsigned)__builtin_amdgcn_update_dpp(-1, (int)v, 0x142, 0xF, 0xF, false); // row_bcast:15
    v = t < v ? t : v;
    t = (unsigned)__builtin_amdgcn_update_dpp(-1, (int)v, 0x143, 0xF, 0xF, false); // row_bcast:31
    v = t < v ? t : v;
    return v;
}

// One block per series. Prim with packed (d2|idx) u32 candidates.
// ROUND-6 DELTA (theory: polled mailbox suffered retry-quantization
// oscillation — any wave publishing earlier than the last publisher by
// < 1 LDS round-trip had its in-flight poll read fail -> +~130cy retry,
// and the retry grid skewed next iteration's publish times, sustaining
// the oscillation; ~300 cy/iter of the 868 measured were unexplained by
// the deterministic chain):
//   * mailbox -> barrier-synced exchange: lane63 ds_write, __syncthreads
//     (drains write + realigns all 4 waves every iteration), single
//     uint4 broadcast read. No tags, no bit-11 sentinel, no retries.
//     Double-buffered slots keep a 2-iteration WAR safety margin.
//   * loss fused into the last-finishing block via device-scope counter
//     (release fence before add, acquire after — cross-XCD L2 per G16),
//     removing 2 kernel launches + gaps (~48 us) for ~10 us in-block work.
__global__ __launch_bounds__(TPB)
void topo_kernel(const float* __restrict__ pred,
                 const float* __restrict__ tgt,
                 float* __restrict__ topo /* [64][N_DEATH] */,
                 unsigned* __restrict__ ctr,
                 int fuse,
                 float* __restrict__ out) {
    __shared__ float4 pp[SORT_N];
    __shared__ float deaths[SORT_N];     // raw d2 during Prim
    __shared__ __align__(16) unsigned xslot[2 * NW];  // [buf][wave]
    __shared__ unsigned lastflag;

    const int b = blockIdx.x;
    const float* x = (b < BATCH) ? (pred + b * LLEN) : (tgt + (b - BATCH) * LLEN);
    const int t = threadIdx.x;
    const int lane = t & 63;
    const int wid = t >> 6;

    float px[PT], py[PT], pz[PT];
    unsigned m[PT];      // packed running min-distance (d2_hi20 | 0 | idx)
    unsigned idxs[PT];
    unsigned vis = 0;    // bit s: vertex t*PT+s is visited (or padding)
#pragma unroll
    for (int s = 0; s < PT; ++s) {
        int idx = t * PT + s;
        idxs[s] = (unsigned)idx;
        bool valid = idx < N_PTS;
        px[s] = valid ? x[idx]     : 0.f;
        py[s] = valid ? x[idx + 1] : 0.f;
        pz[s] = valid ? x[idx + 2] : 0.f;
        pp[idx] = make_float4(px[s], py[s], pz[s], 0.f);
        m[s] = 0x7F800000u | idxs[s];           // +inf packed
        if (!valid || idx == 0) vis |= 1u << s; // pads + start vertex visited
    }
    __syncthreads();   // pp[] visible

    float pjx = x[0], pjy = x[1], pjz = x[2];

    for (int i = 0; i < N_DEATH; ++i) {
        // fused: min-update with distance to j + masked local argmin.
        unsigned lv0 = 0xFFFFFFFFu, lv1 = 0xFFFFFFFFu;
#pragma unroll
        for (int s = 0; s < PT; ++s) {
            float dx = px[s] - pjx, dy = py[s] - pjy, dz = pz[s] - pjz;
            float d2 = dx * dx + dy * dy + dz * dz;
            // (d2 & 0xFFFFF000) | idx -> single v_and_or_b32
            unsigned pk = (__float_as_uint(d2) & 0xFFFFF000u) | idxs[s];
            unsigned nm = m[s] < pk ? m[s] : pk;
            m[s] = nm;
            // sext of visited bit s -> 0 or 0xFFFFFFFF; visited cands lose
            unsigned ext = (unsigned)__builtin_amdgcn_sbfe((int)vis, s, 1);
            unsigned cand = nm | ext;
            if (s & 1) lv1 = lv1 < cand ? lv1 : cand;
            else       lv0 = lv0 < cand ? lv0 : cand;
        }
        unsigned lv = lv0 < lv1 ? lv0 : lv1;
        unsigned wmin = dpp_umin6(lv);           // valid in lane 63
        const int base = (i & 1) * NW;
        if (lane == 63) xslot[base + wid] = wmin;
        __syncthreads();                          // drain write + realign waves
        const uint4 q = *(const uint4*)&xslot[base];  // one b128 broadcast read
        unsigned w01 = q.x < q.y ? q.x : q.y;
        unsigned w23 = q.z < q.w ? q.z : q.w;
        unsigned win = w01 < w23 ? w01 : w23;
        int j = (int)(win & 0x7FFu);
        // mark new j visited in its owner thread
        vis |= (t == (j >> 3)) ? (1u << (j & 7)) : 0u;
        float4 pj = pp[j];                       // broadcast read, conflict-free
        pjx = pj.x; pjy = pj.y; pjz = pj.z;
        if (t == 0) deaths[i] = __uint_as_float(win & 0xFFFFF000u); // raw d2
    }

    // pad then bitonic sort DESCENDING on d2 (sqrt is monotone -> same order)
    if (t < SORT_N - N_DEATH) deaths[N_DEATH + t] = -BIG;
    __syncthreads();

    for (int k = 2; k <= SORT_N; k <<= 1) {
        for (int jj = k >> 1; jj > 0; jj >>= 1) {
#pragma unroll
            for (int s = 0; s < SORT_N / TPB; ++s) {
                int ii = t + s * TPB;
                int ixj = ii ^ jj;
                if (ixj > ii) {
                    float a = deaths[ii], c = deaths[ixj];
                    bool descBlock = ((ii & k) == 0);
                    bool doSwap = descBlock ? (a < c) : (a > c);
                    if (doSwap) { deaths[ii] = c; deaths[ixj] = a; }
                }
            }
            __syncthreads();
        }
    }

    for (int e = t; e < N_DEATH; e += TPB)
        topo[b * N_DEATH + e] = sqrtf(deaths[e]);   // sqrt deferred to here

    if (!fuse) return;

    // ---- fused loss: last-finishing block computes the full reduction ----
    __syncthreads();   // all topo stores drained (vmcnt=0 per wave at barrier)
    if (t == 0) {
        __threadfence();   // agent release: write back L2 so other XCDs see topo
        unsigned prev = __hip_atomic_fetch_add(ctr, 1u, __ATOMIC_ACQ_REL,
                                               __HIP_MEMORY_SCOPE_AGENT);
        lastflag = (prev == 63u) ? 1u : 0u;
        __threadfence();   // acquire side: invalidate before cross-XCD reads
    }
    __syncthreads();
    if (lastflag == 0u) return;

    // last block: MSE over pred/tgt + topo loss, deterministic order
    float msum = 0.f;
    const float4* p4 = (const float4*)pred;
    const float4* t4 = (const float4*)tgt;
    for (int e = t; e < (BATCH * LLEN) / 4; e += TPB) {   // 16384 float4 pairs
        float4 a = p4[e], c = t4[e];
        float dx = a.x - c.x, dy = a.y - c.y, dz = a.z - c.z, dw = a.w - c.w;
        msum += dx * dx + dy * dy + dz * dz + dw * dw;
    }
    float tsum = 0.f;
    const float4* q4 = (const float4*)topo;
    const int nt4 = (BATCH * N_DEATH) / 4;   // 16360 (65440 % 4 == 0)
    for (int e = t; e < nt4; e += TPB) {
        float4 a = q4[e], c = q4[e + nt4];
        float dx = a.x - c.x, dy = a.y - c.y, dz = a.z - c.z, dw = a.w - c.w;
        tsum += dx * dx + dy * dy + dz * dz + dw * dw;
    }
    __shared__ float sm[2][NW];
#pragma unroll
    for (int off = 32; off >= 1; off >>= 1) {
        msum += __shfl_xor(msum, off);
        tsum += __shfl_xor(tsum, off);
    }
    if (lane == 0) { sm[0][wid] = msum; sm[1][wid] = tsum; }
    __syncthreads();
    if (t == 0) {
        float M = 0.f, T = 0.f;
#pragma unroll
        for (int w = 0; w < NW; ++w) { M += sm[0][w]; T += sm[1][w]; }
        out[0] = M / (float)(BATCH * LLEN) + 0.1f * (T / (float)(BATCH * N_DEATH));
    }
}

// Fallback: single-block deterministic reduction (if ws can't hold the counter)
#define RTPB 1024
__global__ __launch_bounds__(RTPB)
void loss_kernel(const float* __restrict__ pred,
                 const float* __restrict__ tgt,
                 const float* __restrict__ topo,
                 float* __restrict__ out) {
    const int t = threadIdx.x;
    float msum = 0.f;
    const float4* p4 = (const float4*)pred;
    const float4* t4 = (const float4*)tgt;
    const int n4 = (BATCH * LLEN) / 4;   // 16384
    for (int e = t; e < n4; e += RTPB) {
        float4 a = p4[e], c = t4[e];
        float dx = a.x - c.x, dy = a.y - c.y, dz = a.z - c.z, dw = a.w - c.w;
        msum += dx * dx + dy * dy + dz * dz + dw * dw;
    }
    float tsum = 0.f;
    const int nt = BATCH * N_DEATH;      // 65440
    for (int e = t; e < nt; e += RTPB) {
        float d = topo[e] - topo[e + nt];
        tsum += d * d;
    }
    __shared__ float sm[2][RTPB / 64];
#pragma unroll
    for (int off = 32; off >= 1; off >>= 1) {
        msum += __shfl_xor(msum, off);
        tsum += __shfl_xor(tsum, off);
    }
    int lane = t & 63, wid = t >> 6;
    if (lane == 0) { sm[0][wid] = msum; sm[1][wid] = tsum; }
    __syncthreads();
    if (t == 0) {
        float M = 0.f, T = 0.f;
#pragma unroll
        for (int w = 0; w < RTPB / 64; ++w) { M += sm[0][w]; T += sm[1][w]; }
        out[0] = M / (float)(BATCH * LLEN) + 0.1f * (T / (float)nt);
    }
}

extern "C" void kernel_launch(void* const* d_in, const int* in_sizes, int n_in,
                              void* d_out, int out_size, void* d_ws, size_t ws_size,
                              hipStream_t stream) {
    const float* pred = (const float*)d_in[0];
    const float* tgt  = (const float*)d_in[1];
    float* topo = (float*)d_ws;
    unsigned* ctr = (unsigned*)((char*)d_ws + TOPO_BYTES);
    const int fuse = (ws_size >= TOPO_BYTES + sizeof(unsigned)) ? 1 : 0;

    if (fuse) hipMemsetAsync(ctr, 0, sizeof(unsigned), stream);  // re-arm per replay

    topo_kernel<<<2 * BATCH, TPB, 0, stream>>>(pred, tgt, topo,
                                               fuse ? ctr : nullptr, fuse,
                                               (float*)d_out);
    if (!fuse)
        loss_kernel<<<1, RTPB, 0, stream>>>(pred, tgt, topo, (float*)d_out);
}

// Round 2
// 708.874 us; speedup vs baseline: 1.1335x; 1.1098x over previous
//
#include <hip/hip_runtime.h>
#include <math.h>

// Problem constants (reference: B=32, L=2048)
#define LLEN 2048
#define BATCH 32
#define N_PTS (LLEN - 2)     // 2046 embedded points
#define N_DEATH (LLEN - 3)   // 2045 MST edges / deaths
#define SORT_N 2048
#define TPB 256              // 4 waves, one per SIMD
#define PT 8                 // elements per thread
#define NW 4                 // waves per block
#define BIG 1e30f
#define TOPO_BYTES ((size_t)64 * N_DEATH * 4)   // 523,520 B

typedef float v2f __attribute__((ext_vector_type(2)));

// Wave64 unsigned-min via DPP (VALU pipe). Result valid in lane 63.
__device__ __forceinline__ unsigned dpp_umin6(unsigned v) {
    unsigned t;
    t = (unsigned)__builtin_amdgcn_update_dpp(-1, (int)v, 0x111, 0xF, 0xF, false); // row_shr:1
    v = t < v ? t : v;
    t = (unsigned)__builtin_amdgcn_update_dpp(-1, (int)v, 0x112, 0xF, 0xF, false); // row_shr:2
    v = t < v ? t : v;
    t = (unsigned)__builtin_amdgcn_update_dpp(-1, (int)v, 0x114, 0xF, 0xF, false); // row_shr:4
    v = t < v ? t : v;
    t = (unsigned)__builtin_amdgcn_update_dpp(-1, (int)v, 0x118, 0xF, 0xF, false); // row_shr:8
    v = t < v ? t : v;
    t = (unsigned)__builtin_amdgcn_update_dpp(-1, (int)v, 0x142, 0xF, 0xF, false); // row_bcast:15
    v = t < v ? t : v;
    t = (unsigned)__builtin_amdgcn_update_dpp(-1, (int)v, 0x143, 0xF, 0xF, false); // row_bcast:31
    v = t < v ? t : v;
    return v;
}

// One block per series. Prim with packed (d2|idx) u32 candidates.
// ROUND-7 DELTA (post-mortem r6: barrier exchange ~= polled mailbox, 867
// cyc/iter; the chain model says the two remaining big levers are the
// pre-barrier lgkmcnt(0) write-drain (~130cy, forced by __syncthreads
// semantics) and the scan's 88-inst VALU issue):
//   * raw `s_barrier` via inline asm ("memory" clobber) — NO lgkmcnt(0)
//     drain before it. DS unit services ops in arrival order within the
//     CU: lane63's ds_write (issued pre-arrival) completes before any
//     post-release read. Double-buffered slots keep WAR separation of a
//     full barrier. (If DS isn't FIFO across waves this FAILS verify ->
//     revert next round.)
//   * packed-FP32 scan: dx/dy/dz/d2 for 2 points per VOP3P inst
//     (v_pk_add/mul/fma_f32) via float2 ext vectors; 88 -> ~64 inst.
__global__ __launch_bounds__(TPB)
void topo_kernel(const float* __restrict__ pred,
                 const float* __restrict__ tgt,
                 float* __restrict__ topo /* [64][N_DEATH] */,
                 unsigned* __restrict__ ctr,
                 int fuse,
                 float* __restrict__ out) {
    __shared__ float4 pp[SORT_N];
    __shared__ float deaths[SORT_N];     // raw d2 during Prim
    __shared__ __align__(16) unsigned xslot[2 * NW];  // [buf][wave]
    __shared__ unsigned lastflag;

    const int b = blockIdx.x;
    const float* x = (b < BATCH) ? (pred + b * LLEN) : (tgt + (b - BATCH) * LLEN);
    const int t = threadIdx.x;
    const int lane = t & 63;
    const int wid = t >> 6;

    v2f px2[PT / 2], py2[PT / 2], pz2[PT / 2];
    unsigned m[PT];      // packed running min-distance (d2_hi20 | 0 | idx)
    unsigned idxs[PT];
    unsigned vis = 0;    // bit s: vertex t*PT+s is visited (or padding)
#pragma unroll
    for (int s = 0; s < PT; ++s) {
        int idx = t * PT + s;
        idxs[s] = (unsigned)idx;
        bool valid = idx < N_PTS;
        float vx = valid ? x[idx]     : 0.f;
        float vy = valid ? x[idx + 1] : 0.f;
        float vz = valid ? x[idx + 2] : 0.f;
        if (s & 1) { px2[s >> 1].y = vx; py2[s >> 1].y = vy; pz2[s >> 1].y = vz; }
        else       { px2[s >> 1].x = vx; py2[s >> 1].x = vy; pz2[s >> 1].x = vz; }
        pp[idx] = make_float4(vx, vy, vz, 0.f);
        m[s] = 0x7F800000u | idxs[s];           // +inf packed
        if (!valid || idx == 0) vis |= 1u << s; // pads + start vertex visited
    }
    __syncthreads();   // pp[] visible (real barrier, with drain)

    float pjx = x[0], pjy = x[1], pjz = x[2];

    for (int i = 0; i < N_DEATH; ++i) {
        // fused: min-update with distance to j + masked local argmin.
        // Distance part packed 2-wide (VOP3P f32); key part scalar u32.
        v2f jx = {pjx, pjx}, jy = {pjy, pjy}, jz = {pjz, pjz};
        unsigned lv0 = 0xFFFFFFFFu, lv1 = 0xFFFFFFFFu;
#pragma unroll
        for (int k = 0; k < PT / 2; ++k) {
            v2f dx = px2[k] - jx, dy = py2[k] - jy, dz = pz2[k] - jz;
            v2f d2 = dx * dx + dy * dy + dz * dz;
            unsigned pk0 = (__float_as_uint(d2.x) & 0xFFFFF000u) | idxs[2 * k];
            unsigned pk1 = (__float_as_uint(d2.y) & 0xFFFFF000u) | idxs[2 * k + 1];
            unsigned nm0 = m[2 * k] < pk0 ? m[2 * k] : pk0;
            unsigned nm1 = m[2 * k + 1] < pk1 ? m[2 * k + 1] : pk1;
            m[2 * k] = nm0;
            m[2 * k + 1] = nm1;
            unsigned e0 = (unsigned)__builtin_amdgcn_sbfe((int)vis, 2 * k, 1);
            unsigned e1 = (unsigned)__builtin_amdgcn_sbfe((int)vis, 2 * k + 1, 1);
            unsigned c0 = nm0 | e0, c1 = nm1 | e1;
            lv0 = lv0 < c0 ? lv0 : c0;
            lv1 = lv1 < c1 ? lv1 : c1;
        }
        unsigned lv = lv0 < lv1 ? lv0 : lv1;
        unsigned wmin = dpp_umin6(lv);           // valid in lane 63
        const int base = (i & 1) * NW;
        if (lane == 63) xslot[base + wid] = wmin;
        // raw barrier: no lgkmcnt(0) drain of the publish write. DS-FIFO
        // ordering makes the write visible to post-release readers.
        asm volatile("s_barrier" ::: "memory");
        const uint4 q = *(const uint4*)&xslot[base];  // one b128 broadcast read
        unsigned w01 = q.x < q.y ? q.x : q.y;
        unsigned w23 = q.z < q.w ? q.z : q.w;
        unsigned win = w01 < w23 ? w01 : w23;
        int j = (int)(win & 0x7FFu);
        // mark new j visited in its owner thread
        vis |= (t == (j >> 3)) ? (1u << (j & 7)) : 0u;
        float4 pj = pp[j];                       // broadcast read, conflict-free
        pjx = pj.x; pjy = pj.y; pjz = pj.z;
        if (t == 0) deaths[i] = __uint_as_float(win & 0xFFFFF000u); // raw d2
    }

    // pad then bitonic sort DESCENDING on d2 (sqrt is monotone -> same order)
    if (t < SORT_N - N_DEATH) deaths[N_DEATH + t] = -BIG;
    __syncthreads();

    for (int k = 2; k <= SORT_N; k <<= 1) {
        for (int jj = k >> 1; jj > 0; jj >>= 1) {
#pragma unroll
            for (int s = 0; s < SORT_N / TPB; ++s) {
                int ii = t + s * TPB;
                int ixj = ii ^ jj;
                if (ixj > ii) {
                    float a = deaths[ii], c = deaths[ixj];
                    bool descBlock = ((ii & k) == 0);
                    bool doSwap = descBlock ? (a < c) : (a > c);
                    if (doSwap) { deaths[ii] = c; deaths[ixj] = a; }
                }
            }
            __syncthreads();
        }
    }

    for (int e = t; e < N_DEATH; e += TPB)
        topo[b * N_DEATH + e] = sqrtf(deaths[e]);   // sqrt deferred to here

    if (!fuse) return;

    // ---- fused loss: last-finishing block computes the full reduction ----
    __syncthreads();   // all topo stores drained (vmcnt=0 per wave at barrier)
    if (t == 0) {
        __threadfence();   // agent release: write back L2 so other XCDs see topo
        unsigned prev = __hip_atomic_fetch_add(ctr, 1u, __ATOMIC_ACQ_REL,
                                               __HIP_MEMORY_SCOPE_AGENT);
        lastflag = (prev == 63u) ? 1u : 0u;
        __threadfence();   // acquire side: invalidate before cross-XCD reads
    }
    __syncthreads();
    if (lastflag == 0u) return;

    // last block: MSE over pred/tgt + topo loss, deterministic order
    float msum = 0.f;
    const float4* p4 = (const float4*)pred;
    const float4* t4 = (const float4*)tgt;
    for (int e = t; e < (BATCH * LLEN) / 4; e += TPB) {   // 16384 float4 pairs
        float4 a = p4[e], c = t4[e];
        float dx = a.x - c.x, dy = a.y - c.y, dz = a.z - c.z, dw = a.w - c.w;
        msum += dx * dx + dy * dy + dz * dz + dw * dw;
    }
    float tsum = 0.f;
    const float4* q4 = (const float4*)topo;
    const int nt4 = (BATCH * N_DEATH) / 4;   // 16360 (65440 % 4 == 0)
    for (int e = t; e < nt4; e += TPB) {
        float4 a = q4[e], c = q4[e + nt4];
        float dx = a.x - c.x, dy = a.y - c.y, dz = a.z - c.z, dw = a.w - c.w;
        tsum += dx * dx + dy * dy + dz * dz + dw * dw;
    }
    __shared__ float sm[2][NW];
#pragma unroll
    for (int off = 32; off >= 1; off >>= 1) {
        msum += __shfl_xor(msum, off);
        tsum += __shfl_xor(tsum, off);
    }
    if (lane == 0) { sm[0][wid] = msum; sm[1][wid] = tsum; }
    __syncthreads();
    if (t == 0) {
        float M = 0.f, T = 0.f;
#pragma unroll
        for (int w = 0; w < NW; ++w) { M += sm[0][w]; T += sm[1][w]; }
        out[0] = M / (float)(BATCH * LLEN) + 0.1f * (T / (float)(BATCH * N_DEATH));
    }
}

// Fallback: single-block deterministic reduction (if ws can't hold the counter)
#define RTPB 1024
__global__ __launch_bounds__(RTPB)
void loss_kernel(const float* __restrict__ pred,
                 const float* __restrict__ tgt,
                 const float* __restrict__ topo,
                 float* __restrict__ out) {
    const int t = threadIdx.x;
    float msum = 0.f;
    const float4* p4 = (const float4*)pred;
    const float4* t4 = (const float4*)tgt;
    const int n4 = (BATCH * LLEN) / 4;   // 16384
    for (int e = t; e < n4; e += RTPB) {
        float4 a = p4[e], c = t4[e];
        float dx = a.x - c.x, dy = a.y - c.y, dz = a.z - c.z, dw = a.w - c.w;
        msum += dx * dx + dy * dy + dz * dz + dw * dw;
    }
    float tsum = 0.f;
    const int nt = BATCH * N_DEATH;      // 65440
    for (int e = t; e < nt; e += RTPB) {
        float d = topo[e] - topo[e + nt];
        tsum += d * d;
    }
    __shared__ float sm[2][RTPB / 64];
#pragma unroll
    for (int off = 32; off >= 1; off >>= 1) {
        msum += __shfl_xor(msum, off);
        tsum += __shfl_xor(tsum, off);
    }
    int lane = t & 63, wid = t >> 6;
    if (lane == 0) { sm[0][wid] = msum; sm[1][wid] = tsum; }
    __syncthreads();
    if (t == 0) {
        float M = 0.f, T = 0.f;
#pragma unroll
        for (int w = 0; w < RTPB / 64; ++w) { M += sm[0][w]; T += sm[1][w]; }
        out[0] = M / (float)(BATCH * LLEN) + 0.1f * (T / (float)nt);
    }
}

extern "C" void kernel_launch(void* const* d_in, const int* in_sizes, int n_in,
                              void* d_out, int out_size, void* d_ws, size_t ws_size,
                              hipStream_t stream) {
    const float* pred = (const float*)d_in[0];
    const float* tgt  = (const float*)d_in[1];
    float* topo = (float*)d_ws;
    unsigned* ctr = (unsigned*)((char*)d_ws + TOPO_BYTES);
    const int fuse = (ws_size >= TOPO_BYTES + sizeof(unsigned)) ? 1 : 0;

    if (fuse) hipMemsetAsync(ctr, 0, sizeof(unsigned), stream);  // re-arm per replay

    topo_kernel<<<2 * BATCH, TPB, 0, stream>>>(pred, tgt, topo,
                                               fuse ? ctr : nullptr, fuse,
                                               (float*)d_out);
    if (!fuse)
        loss_kernel<<<1, RTPB, 0, stream>>>(pred, tgt, topo, (float*)d_out);
}